// Round 5
// baseline (1495.921 us; speedup 1.0000x reference)
//
#include <hip/hip_runtime.h>

// VectorQuantizer on MI355X (gfx950) — MFMA coarse argmin + f64 exact refine
// inputs:  d_in[0] = inputs  [32,64,64,64] f32 (NCHW)
//          d_in[1] = embedding [512,64] f32
//          d_in[2] = weight [512] f32
// output (all f32, concatenated):
//          [0 .. 8388607]   quantized NCHW
//          [8388608]        commitment_loss
//          [8388609]        perplexity
//          [8388610]        usage
//          [8388611 .. ]    indices (131072, written as float)

typedef __attribute__((ext_vector_type(8))) short bf16x8;
typedef __attribute__((ext_vector_type(4))) float f32x4;
typedef unsigned int uint;
typedef unsigned short ushort;

namespace {
constexpr int kC = 64, kH = 64, kW = 64;
constexpr int kK = 512, kD = 64;
constexpr int kHW = kH * kW;                  // 4096
constexpr int kCHW = kC * kHW;                // 262144
constexpr int kN = 32 * kHW;                  // 131072
constexpr int kQElems = 32 * kC * kHW;        // 8388608
constexpr float kGapThresh = 0.5f;            // >>18 sigma of bf16 dot error
}

__device__ __forceinline__ ushort f2bf(float f) {
  const uint u = __float_as_uint(f);
  return (ushort)((u + 0x7FFFu + ((u >> 16) & 1u)) >> 16);  // RNE
}

// ---- kernel 0: E->bf16 + enorm(f32) + zero counters --------------------------
__global__ __launch_bounds__(512) void vq_prep(const float* __restrict__ emb,
                                               ushort* __restrict__ emb_bf,
                                               float* __restrict__ enorm,
                                               uint* __restrict__ counts,
                                               uint* __restrict__ flag_count) {
  const int t = threadIdx.x;
#pragma unroll
  for (int i = 0; i < (kK * kD) / 512; ++i) {   // coalesced convert
    const int e = t + i * 512;
    emb_bf[e] = f2bf(emb[e]);
  }
  const float* __restrict__ ep = emb + t * kD;  // L1/L2-hot second pass
  float s = 0.f;
#pragma unroll
  for (int d = 0; d < kD; ++d) s = fmaf(ep[d], ep[d], s);
  enorm[t] = s;
  counts[t] = 0u;
  if (t == 0) *flag_count = 0u;
}

// ---- kernel 1: MFMA coarse argmin (bf16) + top-2 gap flagging ----------------
// Block = 256 thr = 4 waves, 64 points, all 512 codes (two 256-code LDS halves).
// Wave wv covers codes {wv*64..wv*64+63} in each half. s = enorm - 2*X.E^T via
// mfma_f32_16x16x32_bf16; C/D layout: col=lane&15 (code), row=(lane>>4)*4+reg.
__global__ __launch_bounds__(256, 2) void vq_assign(
    const float* __restrict__ in, const ushort* __restrict__ emb_bf,
    const float* __restrict__ enorm, float* __restrict__ idx_out,
    uint* __restrict__ flag_count, uint* __restrict__ flags, uint flag_cap) {
  __shared__ ushort eb[256 * 64];   // 32 KiB E half-tile, XOR-swizzled rows
  __shared__ ushort xb[64 * 64];    // 8 KiB  X tile,     XOR-swizzled rows
  __shared__ float mb[4][64], ms[4][64];
  __shared__ int   mi[4][64];

  const int tid = threadIdx.x;
  const int lane = tid & 63;
  const int wv = __builtin_amdgcn_readfirstlane(tid >> 6);
  const int c = lane & 15;   // tile col (code)
  const int g = lane >> 4;   // 0..3

  const int blk = blockIdx.x;
  const int bb = blk >> 6;                 // batch
  const int hw0 = (blk & 63) << 6;         // 64 contiguous hw points
  const float* __restrict__ xp = in + (size_t)bb * kCHW + hw0;

  // prefetch per-lane enorm for this wave's 8 col-tiles (coalesced, L2-hot)
  float en_pre[8];
#pragma unroll
  for (int h = 0; h < 2; ++h)
#pragma unroll
    for (int ct = 0; ct < 4; ++ct)
      en_pre[h * 4 + ct] = enorm[h * 256 + wv * 64 + ct * 16 + c];

  // ---- stage X tile: wave wv converts d in [wv*16, wv*16+16) for all 64 pts
  {
    const int p = lane;
    uint u[8];
#pragma unroll
    for (int j = 0; j < 8; ++j) {
      const float f0 = xp[(size_t)(wv * 16 + 2 * j    ) * kHW + p];
      const float f1 = xp[(size_t)(wv * 16 + 2 * j + 1) * kHW + p];
      u[j] = (uint)f2bf(f0) | ((uint)f2bf(f1) << 16);
    }
    const int swz = (p & 7) << 4;
    char* dst = (char*)xb;
    *(uint4*)(dst + ((p * 128 + wv * 32     ) ^ swz)) = uint4{u[0], u[1], u[2], u[3]};
    *(uint4*)(dst + ((p * 128 + wv * 32 + 16) ^ swz)) = uint4{u[4], u[5], u[6], u[7]};
  }

  // ---- stage E half h: 32 KiB block-cooperative copy (coalesced 16B chunks)
  auto stageE = [&](int h) {
    const ushort* __restrict__ src = emb_bf + h * 256 * 64;
#pragma unroll
    for (int i = 0; i < 8; ++i) {
      const int chunk = tid + i * 256;              // 2048 x 16 B
      const int row = chunk >> 3, cc = chunk & 7;
      const uint4 v = *(const uint4*)(src + chunk * 8);
      *(uint4*)((char*)eb + ((row * 128 + cc * 16) ^ ((row & 7) << 4))) = v;
    }
  };
  stageE(0);
  __syncthreads();

  // ---- A-fragments (persist across halves): A[row=rt*16+c][d=g*8+j+s*32]
  bf16x8 af[4][2];
#pragma unroll
  for (int rt = 0; rt < 4; ++rt)
#pragma unroll
    for (int s = 0; s < 2; ++s) {
      const int row = rt * 16 + c;
      af[rt][s] = *(const bf16x8*)(
          (const char*)xb + ((row * 128 + g * 16 + s * 64) ^ ((row & 7) << 4)));
    }

  float tb[16], ts2[16];
  int ti[16];
#pragma unroll
  for (int t16 = 0; t16 < 16; ++t16) { tb[t16] = 3.4e38f; ts2[t16] = 3.4e38f; ti[t16] = 0; }

#pragma unroll
  for (int h = 0; h < 2; ++h) {
    if (h == 1) {
      __syncthreads();   // half-0 eb reads complete
      stageE(1);
      __syncthreads();
    }
#pragma unroll
    for (int ct = 0; ct < 4; ++ct) {
      const int rowb = wv * 64 + ct * 16 + c;       // E row = code (local)
      const int swb = (rowb & 7) << 4;
      const bf16x8 bf0 = *(const bf16x8*)((const char*)eb + ((rowb * 128 + g * 16     ) ^ swb));
      const bf16x8 bf1 = *(const bf16x8*)((const char*)eb + ((rowb * 128 + g * 16 + 64) ^ swb));
      const float en = en_pre[h * 4 + ct];
      const int kidx = h * 256 + wv * 64 + ct * 16 + c;
#pragma unroll
      for (int rt = 0; rt < 4; ++rt) {
        f32x4 acc = {0.f, 0.f, 0.f, 0.f};
        acc = __builtin_amdgcn_mfma_f32_16x16x32_bf16(af[rt][0], bf0, acc, 0, 0, 0);
        acc = __builtin_amdgcn_mfma_f32_16x16x32_bf16(af[rt][1], bf1, acc, 0, 0, 0);
#pragma unroll
        for (int r = 0; r < 4; ++r) {
          const float v = fmaf(-2.f, acc[r], en);   // argmin-equiv distance
          const int t16 = rt * 4 + r;               // point = rt*16 + g*4 + r
          if (v < tb[t16]) { ts2[t16] = tb[t16]; tb[t16] = v; ti[t16] = kidx; }
          else if (v < ts2[t16]) ts2[t16] = v;
        }
      }
    }
  }

  // ---- cross-col reduce: 16 lanes (same g, c=0..15) share each point
#pragma unroll
  for (int t16 = 0; t16 < 16; ++t16) {
    float b = tb[t16], s2 = ts2[t16];
    int i1 = ti[t16];
#pragma unroll
    for (int off = 1; off < 16; off <<= 1) {
      const float ob = __shfl_xor(b, off, 64);
      const float os = __shfl_xor(s2, off, 64);
      const int oi = __shfl_xor(i1, off, 64);
      if (ob < b || (ob == b && oi < i1)) { s2 = fminf(b, os); b = ob; i1 = oi; }
      else                                { s2 = fminf(s2, ob); }
    }
    tb[t16] = b; ts2[t16] = s2; ti[t16] = i1;
  }

  if (c == 0) {
#pragma unroll
    for (int t16 = 0; t16 < 16; ++t16) {
      const int p = (t16 >> 2) * 16 + g * 4 + (t16 & 3);
      mb[wv][p] = tb[t16]; ms[wv][p] = ts2[t16]; mi[wv][p] = ti[t16];
    }
  }
  __syncthreads();

  // ---- cross-wave merge (lowest-k tie-break via idx compare)
  if (tid < 64) {
    float gb = mb[0][tid], gs = ms[0][tid];
    int gi = mi[0][tid];
#pragma unroll
    for (int w2 = 1; w2 < 4; ++w2) {
      const float bw = mb[w2][tid], sw = ms[w2][tid];
      const int iw = mi[w2][tid];
      if (bw < gb || (bw == gb && iw < gi)) { gs = fminf(gb, sw); gb = bw; gi = iw; }
      else                                  { gs = fminf(gs, bw); }
    }
    idx_out[blk * 64 + tid] = (float)gi;
    if (gs - gb < kGapThresh) {   // ambiguous under bf16 -> exact recheck
      const uint slot = atomicAdd(flag_count, 1u);
      if (slot < flag_cap) flags[slot] = (uint)(blk * 64 + tid);
    }
  }
}

// ---- kernel 1b: exact f64 re-argmin, ONE WAVE per flagged point --------------
__global__ __launch_bounds__(256) void vq_refine(const float* __restrict__ in,
                                                 const float* __restrict__ emb,
                                                 const uint* __restrict__ flag_count,
                                                 const uint* __restrict__ flags,
                                                 uint flag_cap,
                                                 float* __restrict__ idx_out) {
  uint cnt = *flag_count;
  if (cnt > flag_cap) cnt = flag_cap;
  const int lane = threadIdx.x & 63;
  const uint wave_id = blockIdx.x * 4u + (threadIdx.x >> 6);
  const uint wave_stride = gridDim.x * 4u;

  for (uint i = wave_id; i < cnt; i += wave_stride) {
    const int n = (int)flags[i];          // wave-uniform
    const int b = n >> 12;
    const int hw = n & 4095;
    const float* __restrict__ xp = in + (size_t)b * kCHW + hw;

    float xr[kD];
#pragma unroll
    for (int d = 0; d < kD; ++d) xr[d] = xp[(size_t)d * kHW];  // uniform -> s_load

    double best = 1e300;
    int bidx = 0;
#pragma unroll
    for (int kk = 0; kk < 8; ++kk) {
      const int k = lane * 8 + kk;
      const float* __restrict__ ep = emb + k * kD;
      double s0 = 0.0, s1 = 0.0;
#pragma unroll
      for (int d = 0; d < kD; d += 2) {
        const double df0 = (double)xr[d] - (double)ep[d];
        const double df1 = (double)xr[d + 1] - (double)ep[d + 1];
        s0 = fma(df0, df0, s0);
        s1 = fma(df1, df1, s1);
      }
      const double s = s0 + s1;
      if (s < best) { best = s; bidx = k; }  // strict < == first-min in-lane
    }
#pragma unroll
    for (int off = 32; off > 0; off >>= 1) {
      const double ob = __shfl_xor(best, off, 64);
      const int oi = __shfl_xor(bidx, off, 64);
      if (ob < best || (ob == best && oi < bidx)) { best = ob; bidx = oi; }
    }
    if (lane == 0) idx_out[n] = (float)bidx;
  }
}

// ---- kernel 2: exact f32 loss partials + histogram from FINAL indices --------
__global__ __launch_bounds__(256) void vq_stats(const float* __restrict__ in,
                                                const float* __restrict__ emb,
                                                const float* __restrict__ idx_f,
                                                uint* __restrict__ counts,
                                                float* __restrict__ partial) {
  __shared__ float red[256];
  __shared__ uint hist[512];
  const int tid = threadIdx.x;
  hist[tid] = 0u; hist[tid + 256] = 0u;
  __syncthreads();

  const int n = blockIdx.x * 256 + tid;
  const int b = n >> 12, hw = n & 4095;
  const float* __restrict__ xp = in + (size_t)b * kCHW + hw;
  const int idx = (int)idx_f[n];
  const float* __restrict__ ep = emb + idx * kD;
  float s = 0.f;
#pragma unroll
  for (int d = 0; d < kD; ++d) {
    const float diff = xp[(size_t)d * kHW] - ep[d];
    s = fmaf(diff, diff, s);
  }
  atomicAdd(&hist[idx], 1u);

  red[tid] = s;
  __syncthreads();
#pragma unroll
  for (int off = 128; off > 0; off >>= 1) {
    if (tid < off) red[tid] += red[tid + off];
    __syncthreads();
  }
  if (tid == 0) partial[blockIdx.x] = red[0];

  // hist complete (atomics precede the reduction barriers)
  if (hist[tid]) atomicAdd(&counts[tid], hist[tid]);
  if (hist[tid + 256]) atomicAdd(&counts[tid + 256], hist[tid + 256]);
}

// ---- kernel 3: scalars --------------------------------------------------------
__global__ __launch_bounds__(512) void vq_finalize(const float* __restrict__ weight,
                                                   const uint* __restrict__ counts,
                                                   const float* __restrict__ partial,
                                                   float* __restrict__ out_scalars) {
  __shared__ float red[512];
  const int t = threadIdx.x;

  const float avg = (float)counts[t] / (float)kN;
  red[t] = avg * logf(avg + 1e-10f);
  __syncthreads();
#pragma unroll
  for (int off = 256; off > 0; off >>= 1) {
    if (t < off) red[t] += red[t + off];
    __syncthreads();
  }
  const float perp = expf(-red[0]);
  __syncthreads();

  red[t] = partial[t];   // exactly 512 stats partials
  __syncthreads();
#pragma unroll
  for (int off = 256; off > 0; off >>= 1) {
    if (t < off) red[t] += red[t + off];
    __syncthreads();
  }
  const float loss = red[0] / (float)((long long)kN * (long long)kD);
  __syncthreads();

  red[t] = (weight[t] >= 0.01f) ? 1.f : 0.f;
  __syncthreads();
#pragma unroll
  for (int off = 256; off > 0; off >>= 1) {
    if (t < off) red[t] += red[t + off];
    __syncthreads();
  }
  if (t == 0) {
    out_scalars[0] = loss;
    out_scalars[1] = perp;
    out_scalars[2] = red[0];
  }
}

// ---- kernel 4: quantized output, NHWC gather -> NCHW store -------------------
__global__ __launch_bounds__(256) void vq_gather(const float* __restrict__ emb,
                                                 const float* __restrict__ idx_f,
                                                 float* __restrict__ outq) {
  const int t = blockIdx.x * 256 + threadIdx.x;  // NCHW linear
  const int w = t & 63;
  const int h = (t >> 6) & 63;
  const int c = (t >> 12) & 63;
  const int b = t >> 18;
  const int n = (b << 12) | (h << 6) | w;
  const int idx = (int)idx_f[n];
  outq[t] = emb[idx * kD + c];                   // L2-resident gather
}

extern "C" void kernel_launch(void* const* d_in, const int* in_sizes, int n_in,
                              void* d_out, int out_size, void* d_ws, size_t ws_size,
                              hipStream_t stream) {
  const float* in = (const float*)d_in[0];
  const float* emb = (const float*)d_in[1];
  const float* weight = (const float*)d_in[2];
  float* out = (float*)d_out;

  // workspace layout (4 B units)
  float* ws_f = (float*)d_ws;
  uint* ws_u = (uint*)d_ws;
  ushort* emb_bf = (ushort*)d_ws;           // [32768] ushort = units [0,16384)
  float* enorm = ws_f + 16384;              // [512]
  uint* counts = ws_u + 16896;              // [512]
  float* partial = ws_f + 17408;            // [512]
  uint* flag_count = ws_u + 17920;          // [1]
  uint* flags = ws_u + 17921;               // [flag_cap]
  const size_t ws_elems = ws_size / 4;
  const uint flag_cap =
      (ws_elems > 17921)
          ? (uint)((ws_elems - 17921 < (size_t)kN) ? ws_elems - 17921 : (size_t)kN)
          : 0u;

  float* outq = out;                    // [8388608]
  float* out_scalars = out + kQElems;   // [3]
  float* idx_out = out + kQElems + 3;   // [131072]

  vq_prep<<<1, 512, 0, stream>>>(emb, emb_bf, enorm, counts, flag_count);
  vq_assign<<<kN / 64, 256, 0, stream>>>(in, emb_bf, enorm, idx_out,
                                         flag_count, flags, flag_cap);
  vq_refine<<<512, 256, 0, stream>>>(in, emb, flag_count, flags, flag_cap, idx_out);
  vq_stats<<<kN / 256, 256, 0, stream>>>(in, emb, idx_out, counts, partial);
  vq_gather<<<kQElems / 256, 256, 0, stream>>>(emb, idx_out, outq);
  vq_finalize<<<1, 512, 0, stream>>>(weight, counts, partial, out_scalars);
}

// Round 6
// 208.965 us; speedup vs baseline: 7.1587x; 7.1587x over previous
//
#include <hip/hip_runtime.h>

// VectorQuantizer on MI355X (gfx950) — split-f16 MFMA argmin + f64 exact refine
// inputs:  d_in[0] = inputs  [32,64,64,64] f32 (NCHW)
//          d_in[1] = embedding [512,64] f32
//          d_in[2] = weight [512] f32
// output (all f32, concatenated):
//          [0 .. 8388607]   quantized NCHW
//          [8388608]        commitment_loss
//          [8388609]        perplexity
//          [8388610]        usage
//          [8388611 .. ]    indices (131072, written as float)

typedef __attribute__((ext_vector_type(8))) _Float16 f16x8;
typedef __attribute__((ext_vector_type(4))) float f32x4;
typedef unsigned int uint;
typedef unsigned short ushort;

namespace {
constexpr int kC = 64, kH = 64, kW = 64;
constexpr int kK = 512, kD = 64;
constexpr int kHW = kH * kW;                  // 4096
constexpr int kCHW = kC * kHW;                // 262144
constexpr int kN = 32 * kHW;                  // 131072
constexpr int kQElems = 32 * kC * kHW;        // 8388608
constexpr float kGapThresh = 0.01f;           // >=10x worst-case split-f16 dot err
}

__device__ __forceinline__ ushort hb(_Float16 h) { return __builtin_bit_cast(ushort, h); }

// ---- kernel 0: E -> f16 hi/lo split + enorm(f32) + zero counters -------------
__global__ __launch_bounds__(512) void vq_prep(const float* __restrict__ emb,
                                               ushort* __restrict__ embh,
                                               ushort* __restrict__ embl,
                                               float* __restrict__ enorm,
                                               uint* __restrict__ counts,
                                               uint* __restrict__ flag_count) {
  const int t = threadIdx.x;
#pragma unroll
  for (int i = 0; i < (kK * kD) / 512; ++i) {   // coalesced split-convert
    const int e = t + i * 512;
    const float f = emb[e];
    const _Float16 h = (_Float16)f;
    const _Float16 l = (_Float16)(f - (float)h);
    embh[e] = hb(h);
    embl[e] = hb(l);
  }
  const float* __restrict__ ep = emb + t * kD;  // L1/L2-hot second pass
  float s = 0.f;
#pragma unroll
  for (int d = 0; d < kD; ++d) s = fmaf(ep[d], ep[d], s);
  enorm[t] = s;
  counts[t] = 0u;
  if (t == 0) *flag_count = 0u;
}

// ---- kernel 1: split-f16 MFMA argmin (f32-accurate) + top-2 gap flagging -----
// Block = 256 thr = 4 waves, 64 points, all 512 codes in four 128-code quarters.
// Wave wv covers codes {wv*32..wv*32+31} of each quarter. dot = xh.eh + xh.el
// + xl.eh (6 MFMA per 16x16 tile). C/D: col=lane&15 (code), row=(lane>>4)*4+reg.
__global__ __launch_bounds__(256, 2) void vq_assign(
    const float* __restrict__ in, const ushort* __restrict__ embh,
    const ushort* __restrict__ embl, const float* __restrict__ enorm,
    float* __restrict__ idx_out, uint* __restrict__ flag_count,
    uint* __restrict__ flags, uint flag_cap) {
  __shared__ ushort ebh[128 * 64];  // 16 KiB E-quarter hi, XOR-swizzled rows
  __shared__ ushort ebl[128 * 64];  // 16 KiB E-quarter lo
  __shared__ ushort xbh[64 * 64];   // 8 KiB  X hi
  __shared__ ushort xbl[64 * 64];   // 8 KiB  X lo
  __shared__ float mb[4][64], ms[4][64];
  __shared__ int   mi[4][64];

  const int tid = threadIdx.x;
  const int lane = tid & 63;
  const int wv = __builtin_amdgcn_readfirstlane(tid >> 6);
  const int c = lane & 15;   // tile col (code)
  const int g = lane >> 4;   // 0..3

  const int blk = blockIdx.x;
  const int bb = blk >> 6;                 // batch
  const int hw0 = (blk & 63) << 6;         // 64 contiguous hw points
  const float* __restrict__ xp = in + (size_t)bb * kCHW + hw0;

  float en_pre[8];
#pragma unroll
  for (int q = 0; q < 4; ++q)
#pragma unroll
    for (int ct = 0; ct < 2; ++ct)
      en_pre[q * 2 + ct] = enorm[q * 128 + wv * 32 + ct * 16 + c];

  // ---- stage X split tiles: wave wv converts d in [wv*16, wv*16+16)
  {
    const int p = lane;
    uint uh[8], ul[8];
#pragma unroll
    for (int j = 0; j < 8; ++j) {
      const float f0 = xp[(size_t)(wv * 16 + 2 * j    ) * kHW + p];
      const float f1 = xp[(size_t)(wv * 16 + 2 * j + 1) * kHW + p];
      const _Float16 h0 = (_Float16)f0, h1 = (_Float16)f1;
      const _Float16 l0 = (_Float16)(f0 - (float)h0);
      const _Float16 l1 = (_Float16)(f1 - (float)h1);
      uh[j] = (uint)hb(h0) | ((uint)hb(h1) << 16);
      ul[j] = (uint)hb(l0) | ((uint)hb(l1) << 16);
    }
    const int swz = (p & 7) << 4;
    const int o0 = (p * 128 + wv * 32) ^ swz;
    const int o1 = (p * 128 + wv * 32 + 16) ^ swz;
    *(uint4*)((char*)xbh + o0) = uint4{uh[0], uh[1], uh[2], uh[3]};
    *(uint4*)((char*)xbh + o1) = uint4{uh[4], uh[5], uh[6], uh[7]};
    *(uint4*)((char*)xbl + o0) = uint4{ul[0], ul[1], ul[2], ul[3]};
    *(uint4*)((char*)xbl + o1) = uint4{ul[4], ul[5], ul[6], ul[7]};
  }

  // ---- stage E quarter q (hi+lo): 1024 x 16 B chunks each, coalesced
  auto stageE = [&](int q) {
#pragma unroll
    for (int i = 0; i < 4; ++i) {
      const int chunk = tid + i * 256;
      const int row = chunk >> 3, cc = chunk & 7;
      const int dsto = (row * 128 + cc * 16) ^ ((row & 7) << 4);
      *(uint4*)((char*)ebh + dsto) = *(const uint4*)(embh + q * 128 * 64 + chunk * 8);
      *(uint4*)((char*)ebl + dsto) = *(const uint4*)(embl + q * 128 * 64 + chunk * 8);
    }
  };
  stageE(0);
  __syncthreads();

  // ---- A-fragments (persist): A[row=rt*16+c][k-chunk g*8 + s*32]
  f16x8 afh[4][2], afl[4][2];
#pragma unroll
  for (int rt = 0; rt < 4; ++rt)
#pragma unroll
    for (int s = 0; s < 2; ++s) {
      const int row = rt * 16 + c;
      const int off = (row * 128 + g * 16 + s * 64) ^ ((row & 7) << 4);
      afh[rt][s] = *(const f16x8*)((const char*)xbh + off);
      afl[rt][s] = *(const f16x8*)((const char*)xbl + off);
    }

  float tb[16], ts2[16];
  int ti[16];
#pragma unroll
  for (int t16 = 0; t16 < 16; ++t16) { tb[t16] = 3.4e38f; ts2[t16] = 3.4e38f; ti[t16] = 0; }

#pragma unroll
  for (int q = 0; q < 4; ++q) {
    if (q) {
      __syncthreads();   // prior-quarter eb reads complete
      stageE(q);
      __syncthreads();
    }
#pragma unroll
    for (int ct = 0; ct < 2; ++ct) {
      const int rowb = wv * 32 + ct * 16 + c;       // E row (quarter-local code)
      const int swb = (rowb & 7) << 4;
      const int ob0 = (rowb * 128 + g * 16) ^ swb;
      const int ob1 = (rowb * 128 + g * 16 + 64) ^ swb;
      const f16x8 bh0 = *(const f16x8*)((const char*)ebh + ob0);
      const f16x8 bh1 = *(const f16x8*)((const char*)ebh + ob1);
      const f16x8 bl0 = *(const f16x8*)((const char*)ebl + ob0);
      const f16x8 bl1 = *(const f16x8*)((const char*)ebl + ob1);
      const float en = en_pre[q * 2 + ct];
      const int kidx = q * 128 + wv * 32 + ct * 16 + c;
#pragma unroll
      for (int rt = 0; rt < 4; ++rt) {
        f32x4 acc = {0.f, 0.f, 0.f, 0.f};
        acc = __builtin_amdgcn_mfma_f32_16x16x32_f16(afh[rt][0], bh0, acc, 0, 0, 0);
        acc = __builtin_amdgcn_mfma_f32_16x16x32_f16(afh[rt][1], bh1, acc, 0, 0, 0);
        acc = __builtin_amdgcn_mfma_f32_16x16x32_f16(afh[rt][0], bl0, acc, 0, 0, 0);
        acc = __builtin_amdgcn_mfma_f32_16x16x32_f16(afh[rt][1], bl1, acc, 0, 0, 0);
        acc = __builtin_amdgcn_mfma_f32_16x16x32_f16(afl[rt][0], bh0, acc, 0, 0, 0);
        acc = __builtin_amdgcn_mfma_f32_16x16x32_f16(afl[rt][1], bh1, acc, 0, 0, 0);
#pragma unroll
        for (int r = 0; r < 4; ++r) {
          const float v = fmaf(-2.f, acc[r], en);   // argmin-equiv distance
          const int t16 = rt * 4 + r;               // point = rt*16 + g*4 + r
          if (v < tb[t16]) { ts2[t16] = tb[t16]; tb[t16] = v; ti[t16] = kidx; }
          else if (v < ts2[t16]) ts2[t16] = v;
        }
      }
    }
  }

  // ---- cross-col reduce: 16 lanes (same g, c=0..15) share each point
#pragma unroll
  for (int t16 = 0; t16 < 16; ++t16) {
    float b = tb[t16], s2 = ts2[t16];
    int i1 = ti[t16];
#pragma unroll
    for (int off = 1; off < 16; off <<= 1) {
      const float ob = __shfl_xor(b, off, 64);
      const float os = __shfl_xor(s2, off, 64);
      const int oi = __shfl_xor(i1, off, 64);
      if (ob < b || (ob == b && oi < i1)) { s2 = fminf(b, os); b = ob; i1 = oi; }
      else                                { s2 = fminf(s2, ob); }
    }
    tb[t16] = b; ts2[t16] = s2; ti[t16] = i1;
  }

  if (c == 0) {
#pragma unroll
    for (int t16 = 0; t16 < 16; ++t16) {
      const int p = (t16 >> 2) * 16 + g * 4 + (t16 & 3);
      mb[wv][p] = tb[t16]; ms[wv][p] = ts2[t16]; mi[wv][p] = ti[t16];
    }
  }
  __syncthreads();

  // ---- cross-wave merge (lowest-k tie-break)
  if (tid < 64) {
    float gb = mb[0][tid], gs = ms[0][tid];
    int gi = mi[0][tid];
#pragma unroll
    for (int w2 = 1; w2 < 4; ++w2) {
      const float bw = mb[w2][tid], sw = ms[w2][tid];
      const int iw = mi[w2][tid];
      if (bw < gb || (bw == gb && iw < gi)) { gs = fminf(gb, sw); gb = bw; gi = iw; }
      else                                  { gs = fminf(gs, bw); }
    }
    idx_out[blk * 64 + tid] = (float)gi;
    if (gs - gb < kGapThresh) {   // genuine near-tie -> exact recheck
      const uint slot = atomicAdd(flag_count, 1u);
      if (slot < flag_cap) flags[slot] = (uint)(blk * 64 + tid);
    }
  }
}

// ---- kernel 1b: exact f64 re-argmin, ONE WAVE per flagged point --------------
// unroll 1 on the code loop: keeps VGPR ~110, no spills (round-5 lesson).
__global__ __launch_bounds__(256) void vq_refine(const float* __restrict__ in,
                                                 const float* __restrict__ emb,
                                                 const uint* __restrict__ flag_count,
                                                 const uint* __restrict__ flags,
                                                 uint flag_cap,
                                                 float* __restrict__ idx_out) {
  uint cnt = *flag_count;
  if (cnt > flag_cap) cnt = flag_cap;
  const int lane = threadIdx.x & 63;
  const uint wave_id = blockIdx.x * 4u + (threadIdx.x >> 6);
  const uint wave_stride = gridDim.x * 4u;

  for (uint i = wave_id; i < cnt; i += wave_stride) {
    const int n = (int)flags[i];          // wave-uniform
    const int b = n >> 12;
    const int hw = n & 4095;
    const float* __restrict__ xp = in + (size_t)b * kCHW + hw;

    float xr[kD];
#pragma unroll
    for (int d = 0; d < kD; ++d) xr[d] = xp[(size_t)d * kHW];  // uniform -> s_load

    double best = 1e300;
    int bidx = 0;
#pragma unroll 1
    for (int kk = 0; kk < 8; ++kk) {
      const int k = lane * 8 + kk;
      const float4* __restrict__ ep4 = (const float4*)(emb + k * kD);
      double s0 = 0.0, s1 = 0.0;
#pragma unroll
      for (int j = 0; j < kD / 4; ++j) {
        const float4 e = ep4[j];
        const double d0 = (double)xr[4 * j + 0] - (double)e.x;
        const double d1 = (double)xr[4 * j + 1] - (double)e.y;
        const double d2 = (double)xr[4 * j + 2] - (double)e.z;
        const double d3 = (double)xr[4 * j + 3] - (double)e.w;
        s0 = fma(d0, d0, s0);
        s1 = fma(d1, d1, s1);
        s0 = fma(d2, d2, s0);
        s1 = fma(d3, d3, s1);
      }
      const double s = s0 + s1;
      if (s < best) { best = s; bidx = k; }  // strict < == first-min in-lane
    }
#pragma unroll
    for (int off = 32; off > 0; off >>= 1) {
      const double ob = __shfl_xor(best, off, 64);
      const int oi = __shfl_xor(bidx, off, 64);
      if (ob < best || (ob == best && oi < bidx)) { best = ob; bidx = oi; }
    }
    if (lane == 0) idx_out[n] = (float)bidx;
  }
}

// ---- kernel 2: exact f32 loss partials + histogram from FINAL indices --------
__global__ __launch_bounds__(256) void vq_stats(const float* __restrict__ in,
                                                const float* __restrict__ emb,
                                                const float* __restrict__ idx_f,
                                                uint* __restrict__ counts,
                                                float* __restrict__ partial) {
  __shared__ float red[256];
  __shared__ uint hist[512];
  const int tid = threadIdx.x;
  hist[tid] = 0u; hist[tid + 256] = 0u;
  __syncthreads();

  const int n = blockIdx.x * 256 + tid;
  const int b = n >> 12, hw = n & 4095;
  const float* __restrict__ xp = in + (size_t)b * kCHW + hw;
  const int idx = (int)idx_f[n];
  const float* __restrict__ ep = emb + idx * kD;
  float s = 0.f;
#pragma unroll
  for (int d = 0; d < kD; ++d) {
    const float diff = xp[(size_t)d * kHW] - ep[d];
    s = fmaf(diff, diff, s);
  }
  atomicAdd(&hist[idx], 1u);

  red[tid] = s;
  __syncthreads();
#pragma unroll
  for (int off = 128; off > 0; off >>= 1) {
    if (tid < off) red[tid] += red[tid + off];
    __syncthreads();
  }
  if (tid == 0) partial[blockIdx.x] = red[0];

  if (hist[tid]) atomicAdd(&counts[tid], hist[tid]);
  if (hist[tid + 256]) atomicAdd(&counts[tid + 256], hist[tid + 256]);
}

// ---- kernel 3: scalars -------------------------------------------------------
__global__ __launch_bounds__(512) void vq_finalize(const float* __restrict__ weight,
                                                   const uint* __restrict__ counts,
                                                   const float* __restrict__ partial,
                                                   float* __restrict__ out_scalars) {
  __shared__ float red[512];
  const int t = threadIdx.x;

  const float avg = (float)counts[t] / (float)kN;
  red[t] = avg * logf(avg + 1e-10f);
  __syncthreads();
#pragma unroll
  for (int off = 256; off > 0; off >>= 1) {
    if (t < off) red[t] += red[t + off];
    __syncthreads();
  }
  const float perp = expf(-red[0]);
  __syncthreads();

  red[t] = partial[t];   // exactly 512 stats partials
  __syncthreads();
#pragma unroll
  for (int off = 256; off > 0; off >>= 1) {
    if (t < off) red[t] += red[t + off];
    __syncthreads();
  }
  const float loss = red[0] / (float)((long long)kN * (long long)kD);
  __syncthreads();

  red[t] = (weight[t] >= 0.01f) ? 1.f : 0.f;
  __syncthreads();
#pragma unroll
  for (int off = 256; off > 0; off >>= 1) {
    if (t < off) red[t] += red[t + off];
    __syncthreads();
  }
  if (t == 0) {
    out_scalars[0] = loss;
    out_scalars[1] = perp;
    out_scalars[2] = red[0];
  }
}

// ---- kernel 4: quantized output, NHWC gather -> NCHW store -------------------
__global__ __launch_bounds__(256) void vq_gather(const float* __restrict__ emb,
                                                 const float* __restrict__ idx_f,
                                                 float* __restrict__ outq) {
  const int t = blockIdx.x * 256 + threadIdx.x;  // NCHW linear
  const int w = t & 63;
  const int h = (t >> 6) & 63;
  const int c = (t >> 12) & 63;
  const int b = t >> 18;
  const int n = (b << 12) | (h << 6) | w;
  const int idx = (int)idx_f[n];
  outq[t] = emb[idx * kD + c];                   // L2-resident gather
}

extern "C" void kernel_launch(void* const* d_in, const int* in_sizes, int n_in,
                              void* d_out, int out_size, void* d_ws, size_t ws_size,
                              hipStream_t stream) {
  const float* in = (const float*)d_in[0];
  const float* emb = (const float*)d_in[1];
  const float* weight = (const float*)d_in[2];
  float* out = (float*)d_out;

  // workspace layout (4 B units)
  float* ws_f = (float*)d_ws;
  uint* ws_u = (uint*)d_ws;
  ushort* embh = (ushort*)d_ws;             // [32768] ushort: bytes [0, 64K)
  ushort* embl = embh + kK * kD;            // [32768] ushort: bytes [64K, 128K)
  float* enorm = ws_f + 32768;              // [512]
  uint* counts = ws_u + 33280;              // [512]
  float* partial = ws_f + 33792;            // [512]
  uint* flag_count = ws_u + 34304;          // [1]
  uint* flags = ws_u + 34305;               // [flag_cap]
  const size_t ws_elems = ws_size / 4;
  const uint flag_cap =
      (ws_elems > 34305)
          ? (uint)((ws_elems - 34305 < (size_t)kN) ? ws_elems - 34305 : (size_t)kN)
          : 0u;

  float* outq = out;                    // [8388608]
  float* out_scalars = out + kQElems;   // [3]
  float* idx_out = out + kQElems + 3;   // [131072]

  vq_prep<<<1, 512, 0, stream>>>(emb, embh, embl, enorm, counts, flag_count);
  vq_assign<<<kN / 64, 256, 0, stream>>>(in, embh, embl, enorm, idx_out,
                                         flag_count, flags, flag_cap);
  vq_refine<<<256, 256, 0, stream>>>(in, emb, flag_count, flags, flag_cap, idx_out);
  vq_stats<<<kN / 256, 256, 0, stream>>>(in, emb, idx_out, counts, partial);
  vq_gather<<<kQElems / 256, 256, 0, stream>>>(emb, idx_out, outq);
  vq_finalize<<<1, 512, 0, stream>>>(weight, counts, partial, out_scalars);
}